// Round 9
// baseline (237.727 us; speedup 1.0000x reference)
//
#include <hip/hip_runtime.h>

#define IN_FEAT 128
#define OUT_FEAT 64
#define LRELU_ALPHA 0.2f
#define BUK_SHIFT 7        // coarse bucket = src >> 7 (128 nodes/bucket)
#define BUK_SIZE 128
#define MAX_NBUK 1024      // N <= 131072
#define D_BITS 17          // dst < 2^17: pk = (sl<<17)|dst
#define D_MASK 0x1FFFF
#define BIN_PER_THREAD 16  // 8192 edges per 512-thread bin block
#define CAP 2560           // LDS record capacity per chunk (mean bucket ~2046)
#define STAGE_MAX 5        // CAP / 512

typedef __attribute__((ext_vector_type(8))) short bf16x8;
typedef __attribute__((ext_vector_type(4))) float floatx4;

// fp32 -> bf16 bits, round-to-nearest-even (inputs are finite; no NaN guard)
__device__ __forceinline__ short f2bf(float f) {
  union { float f; unsigned u; } v; v.f = f;
  unsigned r = v.u + 0x7fff + ((v.u >> 16) & 1);
  return (short)(r >> 16);
}
__device__ __forceinline__ float bf2f(unsigned short s) {
  union { unsigned u; float f; } v; v.u = ((unsigned)s) << 16;
  return v.f;
}

// ---------------------------------------------------------------------------
// Kernel 1: h = bf16(x) @ bf16(W) via MFMA 16x16x32. Block = 4 waves = 64 rows.
// Fused: s1 = h@a1, s2 = h@a2 (quad shuffle reduction). h stored as bf16 bits.
// ---------------------------------------------------------------------------
__global__ __launch_bounds__(256) void gemm_mfma_kernel(
    const float* __restrict__ x, const float* __restrict__ W,
    const float* __restrict__ a, unsigned short* __restrict__ h,
    float* __restrict__ s1, float* __restrict__ s2, int N) {
  __shared__ __align__(16) short Wt[64 * 136];  // W^T bf16, stride 136
  __shared__ float a_sh[2 * OUT_FEAT];

  if (threadIdx.x < 2 * OUT_FEAT) a_sh[threadIdx.x] = a[threadIdx.x];
  for (int i = threadIdx.x; i < IN_FEAT * OUT_FEAT; i += 256) {
    int k = i >> 6, n = i & 63;
    Wt[n * 136 + k] = f2bf(W[i]);
  }
  __syncthreads();

  int wave = threadIdx.x >> 6;
  int lane = threadIdx.x & 63;
  int l = lane & 15;
  int quad = lane >> 4;

  int row_base = blockIdx.x * 64 + wave * 16;
  int m = row_base + l;
  int m_c = m < N ? m : N - 1;

  bf16x8 bfrag[4][4];
#pragma unroll
  for (int kt = 0; kt < 4; ++kt)
#pragma unroll
    for (int nt = 0; nt < 4; ++nt)
      bfrag[kt][nt] = *(const bf16x8*)&Wt[(nt * 16 + l) * 136 + kt * 32 + quad * 8];

  floatx4 acc[4] = {floatx4{0,0,0,0}, floatx4{0,0,0,0}, floatx4{0,0,0,0}, floatx4{0,0,0,0}};
  const float* xrow = x + (size_t)m_c * IN_FEAT;
#pragma unroll
  for (int kt = 0; kt < 4; ++kt) {
    float4 xa = *(const float4*)(xrow + kt * 32 + quad * 8);
    float4 xb = *(const float4*)(xrow + kt * 32 + quad * 8 + 4);
    bf16x8 af;
    af[0] = f2bf(xa.x); af[1] = f2bf(xa.y); af[2] = f2bf(xa.z); af[3] = f2bf(xa.w);
    af[4] = f2bf(xb.x); af[5] = f2bf(xb.y); af[6] = f2bf(xb.z); af[7] = f2bf(xb.w);
#pragma unroll
    for (int nt = 0; nt < 4; ++nt)
      acc[nt] = __builtin_amdgcn_mfma_f32_16x16x32_bf16(af, bfrag[kt][nt], acc[nt], 0, 0, 0);
  }

  int out_row = row_base + quad * 4;
#pragma unroll
  for (int reg = 0; reg < 4; ++reg) {
    int r = out_row + reg;
    if (r < N) {
#pragma unroll
      for (int nt = 0; nt < 4; ++nt)
        h[(size_t)r * OUT_FEAT + nt * 16 + l] = (unsigned short)f2bf(acc[nt][reg]);
    }
  }

  float p1[4] = {0, 0, 0, 0}, p2[4] = {0, 0, 0, 0};
#pragma unroll
  for (int nt = 0; nt < 4; ++nt) {
    float a1v = a_sh[nt * 16 + l];
    float a2v = a_sh[OUT_FEAT + nt * 16 + l];
#pragma unroll
    for (int reg = 0; reg < 4; ++reg) {
      p1[reg] += acc[nt][reg] * a1v;
      p2[reg] += acc[nt][reg] * a2v;
    }
  }
#pragma unroll
  for (int off = 1; off < 16; off <<= 1) {
#pragma unroll
    for (int reg = 0; reg < 4; ++reg) {
      p1[reg] += __shfl_xor(p1[reg], off);
      p2[reg] += __shfl_xor(p2[reg], off);
    }
  }
  if (l < 4) {
    int r = out_row + l;
    if (r < N) {
      float v1 = l == 0 ? p1[0] : (l == 1 ? p1[1] : (l == 2 ? p1[2] : p1[3]));
      float v2 = l == 0 ? p2[0] : (l == 1 ? p2[1] : (l == 2 ? p2[2] : p2[3]));
      s1[r] = v1;
      s2[r] = v2;
    }
  }
}

// ---------------------------------------------------------------------------
// Edge coefficients, barrier-free full-TLP kernel: ee[e] = exp(-lrelu(
// s1[src]+s2[dst])). The random s1/s2 gathers (L2-resident, 400KB each) and
// the exp live HERE where thousands of waves hide the latency — not inside
// the barrier-phased fused kernel (round-8 lesson).
// ---------------------------------------------------------------------------
__global__ __launch_bounds__(256) void ee_kernel(
    const int* __restrict__ src, const int* __restrict__ dst,
    const float* __restrict__ s1, const float* __restrict__ s2,
    float* __restrict__ ee, int E) {
  int e = blockIdx.x * 256 + threadIdx.x;
  if (e >= E) return;
  float sc = s1[src[e]] + s2[dst[e]];
  ee[e] = __expf(-(sc > 0.f ? sc : LRELU_ALPHA * sc));
}

// ---------------------------------------------------------------------------
// Coarse histogram over <=1024 buckets: per-block LDS hist, then <=1024 global
// atomics per block onto a 4KB array. No per-edge global atomics.
// ---------------------------------------------------------------------------
__global__ __launch_bounds__(256) void coarse_hist_kernel(
    const int* __restrict__ src, int* __restrict__ cbuk, int E) {
  __shared__ int lh[MAX_NBUK];
  int t = threadIdx.x;
  for (int i = t; i < MAX_NBUK; i += 256) lh[i] = 0;
  __syncthreads();
  for (int e = blockIdx.x * 256 + t; e < E; e += gridDim.x * 256)
    atomicAdd(&lh[src[e] >> BUK_SHIFT], 1);
  __syncthreads();
  for (int i = t; i < MAX_NBUK; i += 256)
    if (lh[i] > 0) atomicAdd(&cbuk[i], lh[i]);
}

// Parallel exclusive scan of bucket counts -> buk_off (NB+1) + bin cursors.
// (Round-8's thread-0 serial loop over 782 entries cost ~6us.)
__global__ __launch_bounds__(1024) void scan_buckets_kernel(
    const int* __restrict__ cbuk, int* __restrict__ buk_off,
    int* __restrict__ buk_cursor, int NB) {
  __shared__ int wsum[16];
  int t = threadIdx.x;
  int lane = t & 63, w = t >> 6;
  int v = (t < NB) ? cbuk[t] : 0;
  int xs = v;
#pragma unroll
  for (int off = 1; off < 64; off <<= 1) {
    int y = __shfl_up(xs, off);
    if (lane >= off) xs += y;
  }
  if (lane == 63) wsum[w] = xs;
  __syncthreads();
  if (t == 0) {
    int run = 0;
#pragma unroll
    for (int i = 0; i < 16; ++i) { int u = wsum[i]; wsum[i] = run; run += u; }
  }
  __syncthreads();
  int excl = wsum[w] + xs - v;
  if (t < NB) {
    buk_off[t] = excl;
    buk_cursor[t] = excl;
  }
  if (t == NB - 1) buk_off[NB] = excl + v;
}

// ---------------------------------------------------------------------------
// Bin by src>>7: bukdata[pos] = int2{ (sl<<17)|dst, ee }. 512 threads, 8192
// edges/block. Per-block LDS histogram + one global atomic per (block,bucket)
// -> ~85B contiguous write runs per bucket (L2-merged). Gather-free.
// ---------------------------------------------------------------------------
__global__ __launch_bounds__(512) void bin_kernel(
    const int* __restrict__ src, const int* __restrict__ dst,
    const float* __restrict__ ee,
    int* __restrict__ buk_cursor, int2* __restrict__ bukdata, int E) {
  __shared__ int lhist[MAX_NBUK];
  __shared__ int lbase[MAX_NBUK];
  int t = threadIdx.x;
  for (int i = t; i < MAX_NBUK; i += 512) lhist[i] = 0;
  __syncthreads();

  int base_e = blockIdx.x * (512 * BIN_PER_THREAD);
  int s[BIN_PER_THREAD], d[BIN_PER_THREAD];
#pragma unroll
  for (int j = 0; j < BIN_PER_THREAD; ++j) {
    int e = base_e + j * 512 + t;
    bool valid = e < E;
    s[j] = valid ? src[e] : 0;
    d[j] = valid ? dst[e] : 0;
    if (valid) atomicAdd(&lhist[s[j] >> BUK_SHIFT], 1);
  }
  __syncthreads();
  for (int i = t; i < MAX_NBUK; i += 512) {
    int c = lhist[i];
    lbase[i] = c > 0 ? atomicAdd(&buk_cursor[i], c) : 0;
    lhist[i] = 0;  // reuse as in-block cursor
  }
  __syncthreads();
#pragma unroll
  for (int j = 0; j < BIN_PER_THREAD; ++j) {
    int e = base_e + j * 512 + t;
    if (e < E) {
      int b = s[j] >> BUK_SHIFT;
      int pos = lbase[b] + atomicAdd(&lhist[b], 1);
      bukdata[pos] = make_int2(((s[j] & (BUK_SIZE - 1)) << D_BITS) | d[j],
                               __float_as_int(ee[e]));
    }
  }
}

// ---------------------------------------------------------------------------
// Fused sort+aggregate: one 512-thread block (8 waves) per 128-node bucket
// (~2048 edges). Staging is now minimal (round-9 change): coalesced 8B load,
// LDS int-hist, block scan, LDS scatter of {h_byte_offset, ee} — no gathers,
// no exp inside the barrier phases. Then each wave aggregates its 16 nodes
// from LDS-resident records: broadcast ds_read + coalesced 128B h gather
// (two wave-halves take alternating edges, 8 gathers in flight). Fused
// finalize: out = elu(acc / rowsum).
// ---------------------------------------------------------------------------
__global__ __launch_bounds__(512) void bucket_sort_aggregate_kernel(
    const int2* __restrict__ bukdata, const int* __restrict__ buk_off,
    const unsigned short* __restrict__ h, float* __restrict__ out, int N) {
  __shared__ int lhist[BUK_SIZE];
  __shared__ int loffs[BUK_SIZE];
  __shared__ int lcur[BUK_SIZE];
  __shared__ int wtot[2];
  __shared__ int2 lrec[CAP];  // 20KB

  int t = threadIdx.x;
  int buk = blockIdx.x;
  int beg = buk_off[buk];
  int end = buk_off[buk + 1];
  int node_base = buk << BUK_SHIFT;

  int wid = t >> 6;      // wave 0..7; owns nodes wid, wid+8, ..., wid+120
  int lane = t & 63;
  int half = lane >> 5;
  int c2 = lane & 31;

  float ax[16], ay[16], rs[16];
#pragma unroll
  for (int j = 0; j < 16; ++j) { ax[j] = 0.f; ay[j] = 0.f; rs[j] = 0.f; }

  for (int cbeg = beg; cbeg < end; cbeg += CAP) {
    int cnt = min(end - cbeg, CAP);

    if (t < BUK_SIZE) lhist[t] = 0;
    __syncthreads();

    // ---- Stage: coalesced record load + LDS histogram ----
    int dreg[STAGE_MAX];
    int slreg[STAGE_MAX];
    int ereg[STAGE_MAX];
#pragma unroll
    for (int j = 0; j < STAGE_MAX; ++j) {
      int i = t + j * 512;
      bool v = i < cnt;
      int2 r = v ? bukdata[cbeg + i] : make_int2(0, 0);
      slreg[j] = (unsigned)r.x >> D_BITS;
      dreg[j] = (r.x & D_MASK) << 7;  // pre-scaled h byte offset (row = 128B)
      ereg[j] = r.y;
      if (v) atomicAdd(&lhist[slreg[j]], 1);
    }
    __syncthreads();

    // ---- Block scan over 128 counters (threads 0..127, 2 waves) ----
    int hv = (t < BUK_SIZE) ? lhist[t] : 0;
    int xs = hv;
#pragma unroll
    for (int off = 1; off < 64; off <<= 1) {
      int y = __shfl_up(xs, off);
      if (lane >= off) xs += y;
    }
    if (t < BUK_SIZE && lane == 63) wtot[t >> 6] = xs;
    __syncthreads();
    if (t < BUK_SIZE) {
      int base = (t >> 6) ? wtot[0] : 0;
      int excl = base + xs - hv;
      loffs[t] = excl;
      lcur[t] = excl;
    }
    __syncthreads();

    // ---- Scatter into LDS, sorted by node ----
#pragma unroll
    for (int j = 0; j < STAGE_MAX; ++j) {
      int i = t + j * 512;
      if (i < cnt) {
        int pos = atomicAdd(&lcur[slreg[j]], 1);
        lrec[pos] = make_int2(dreg[j], ereg[j]);
      }
    }
    __syncthreads();

    // ---- Aggregate: wave walks its 16 nodes' LDS-contiguous records ----
    const char* hb = (const char*)h + 4 * c2;
#pragma unroll
    for (int nn = 0; nn < 16; ++nn) {
      int nl = wid + nn * 8;
      int o = loffs[nl];
      int c = lhist[nl];
      int k = 0;
      for (; k + 8 <= c; k += 8) {
#pragma unroll
        for (int j = 0; j < 4; ++j) {
          int2 r = lrec[o + k + 2 * j + half];  // LDS broadcast per half
          float ee = __int_as_float(r.y);
          unsigned v = *(const unsigned*)(hb + r.x);
          rs[nn] += ee;
          ax[nn] += ee * bf2f(v & 0xffff);
          ay[nn] += ee * bf2f(v >> 16);
        }
      }
      for (int m = k + half; m < c; m += 2) {
        int2 r = lrec[o + m];
        float ee = __int_as_float(r.y);
        unsigned v = *(const unsigned*)(hb + r.x);
        rs[nn] += ee;
        ax[nn] += ee * bf2f(v & 0xffff);
        ay[nn] += ee * bf2f(v >> 16);
      }
    }
    __syncthreads();  // protect lhist/loffs/lrec before next chunk
  }

  // ---- Finalize: cross-half reduce, out = elu(acc / rowsum) ----
#pragma unroll
  for (int nn = 0; nn < 16; ++nn) {
    float r = rs[nn] + __shfl_xor(rs[nn], 32);
    float xv = ax[nn] + __shfl_xor(ax[nn], 32);
    float yv = ay[nn] + __shfl_xor(ay[nn], 32);
    int ng = node_base + wid + nn * 8;
    if (ng < N && half == 0) {
      float vx = xv / r, vy = yv / r;
      vx = vx > 0.f ? vx : __expf(vx) - 1.f;
      vy = vy > 0.f ? vy : __expf(vy) - 1.f;
      *(float2*)&out[(size_t)ng * OUT_FEAT + 2 * c2] = make_float2(vx, vy);
    }
  }
}

extern "C" void kernel_launch(void* const* d_in, const int* in_sizes, int n_in,
                              void* d_out, int out_size, void* d_ws, size_t ws_size,
                              hipStream_t stream) {
  const float* x = (const float*)d_in[0];  // (N, 128) fp32
  const float* W = (const float*)d_in[1];  // (128, 64) fp32
  const float* a = (const float*)d_in[2];  // (1, 128) fp32
  const int* edge = (const int*)d_in[3];   // (2, E) int32

  const int N = in_sizes[0] / IN_FEAT;
  const int E = in_sizes[3] / 2;
  const int* src = edge;
  const int* dst = edge + E;

  float* out = (float*)d_out;  // (N, 64) fp32

  // Workspace layout (~34 MB)
  char* p = (char*)d_ws;
  unsigned short* h = (unsigned short*)p; p += (size_t)N * OUT_FEAT * sizeof(unsigned short);
  float* s1 = (float*)p;      p += (size_t)N * sizeof(float);
  float* s2 = (float*)p;      p += (size_t)N * sizeof(float);
  float* ee = (float*)p;      p += (size_t)E * sizeof(float);
  int* cbuk = (int*)p;        p += MAX_NBUK * sizeof(int);
  int* buk_off = (int*)p;     p += (MAX_NBUK + 1) * sizeof(int);
  int* buk_cursor = (int*)p;  p += MAX_NBUK * sizeof(int);
  int2* bukdata = (int2*)p;   p += (size_t)E * sizeof(int2);

  const int NB = (N + BUK_SIZE - 1) / BUK_SIZE;  // 782 buckets

  hipMemsetAsync(cbuk, 0, MAX_NBUK * sizeof(int), stream);

  int grid_gemm = (N + 63) / 64;
  gemm_mfma_kernel<<<grid_gemm, 256, 0, stream>>>(x, W, a, h, s1, s2, N);

  int grid_e = (E + 255) / 256;
  ee_kernel<<<grid_e, 256, 0, stream>>>(src, dst, s1, s2, ee, E);

  coarse_hist_kernel<<<512, 256, 0, stream>>>(src, cbuk, E);
  scan_buckets_kernel<<<1, 1024, 0, stream>>>(cbuk, buk_off, buk_cursor, NB);

  int grid_bin = (E + 512 * BIN_PER_THREAD - 1) / (512 * BIN_PER_THREAD);
  bin_kernel<<<grid_bin, 512, 0, stream>>>(src, dst, ee, buk_cursor, bukdata, E);

  bucket_sort_aggregate_kernel<<<NB, 512, 0, stream>>>(bukdata, buk_off, h, out, N);
}